// Round 1
// baseline (2067.101 us; speedup 1.0000x reference)
//
#include <hip/hip_runtime.h>
#include <hip/hip_bf16.h>

typedef __hip_bfloat16 bf16;

#define DIM 64
#define BN_EPS 1e-5f

struct ParamPack {
    const void* p[18];
    int n[18];
    int off[18];
};

// ---- read element i of p as float, interpreting per flag (1=bf16, 0=f32) ----
__device__ __forceinline__ float load_as(const void* p, int i, int isbf16) {
    if (isbf16) {
        unsigned short b = ((const unsigned short*)p)[i];
        unsigned int u = ((unsigned int)b) << 16;
        return __uint_as_float(u);
    }
    return ((const float*)p)[i];
}

// ---- dtype detect: scan w1a (values uniform in +-0.125). bf16 interp of real
// bf16 data passes ~100%; bf16 interp of f32 bits passes ~55%. ----
__global__ void gin_detect(const void* w, int nelem, int* flag) {
    const unsigned short* u = (const unsigned short*)w;
    int tid = threadIdx.x;
    int cnt = 0;
    for (int i = tid; i < nelem; i += blockDim.x) {
        unsigned int f = ((unsigned int)u[i]) << 16;
        float v = __uint_as_float(f);
        float av = fabsf(v);
        if (av <= 0.126f && (av == 0.0f || av >= 1e-8f)) cnt++;
    }
    __shared__ int sc[256];
    sc[tid] = cnt;
    __syncthreads();
    for (int s = 128; s > 0; s >>= 1) {
        if (tid < s) sc[tid] += sc[tid + s];
        __syncthreads();
    }
    if (tid == 0) flag[0] = (sc[0] * 10 >= nelem * 9) ? 1 : 0;
}

// ---- stage all 18 param tensors into f32 workspace ----
__global__ void gin_cvt_params(ParamPack pk, float* __restrict__ out,
                               const int* __restrict__ flag) {
    int b = blockIdx.x;
    int f = flag[0];
    const void* p = pk.p[b];
    float* o = out + pk.off[b];
    int n = pk.n[b];
    for (int i = threadIdx.x; i < n; i += blockDim.x) o[i] = load_as(p, i, f);
}

// ---- x -> f32 (named with problem identifier) ----
__global__ void GINEncoder_16114717295311_kernel(const void* __restrict__ x,
                                                 float* __restrict__ h, int n,
                                                 const int* __restrict__ flag) {
    int i = blockIdx.x * blockDim.x + threadIdx.x;
    int f = flag[0];
    if (i < n) h[i] = load_as(x, i, f);
}

__global__ void gin_zero(float* __restrict__ p, int n) {
    int i = blockIdx.x * blockDim.x + threadIdx.x;
    if (i < n) p[i] = 0.0f;
}

// ======================= CSR build (once; graph reused 3x) =======================

// in-degree histogram keyed by dst
__global__ void gin_hist(const int* __restrict__ dst, int* __restrict__ deg, int E) {
    int e = blockIdx.x * blockDim.x + threadIdx.x;
    if (e < E) atomicAdd(&deg[dst[e]], 1);
}

// scan step 1: per-1024-block inclusive scan of deg -> rowptr[i+1]; block sums -> part
__global__ void gin_scan1(const int* __restrict__ deg, int* __restrict__ rowptr,
                          int* __restrict__ part, int N) {
    __shared__ int lds[256];
    int tid = threadIdx.x;
    int base = blockIdx.x * 1024 + tid * 4;
    int a0 = (base + 0 < N) ? deg[base + 0] : 0;
    int a1 = (base + 1 < N) ? deg[base + 1] : 0;
    int a2 = (base + 2 < N) ? deg[base + 2] : 0;
    int a3 = (base + 3 < N) ? deg[base + 3] : 0;
    int s = a0 + a1 + a2 + a3;
    lds[tid] = s;
    __syncthreads();
    for (int off = 1; off < 256; off <<= 1) {
        int v = (tid >= off) ? lds[tid - off] : 0;
        __syncthreads();
        lds[tid] += v;
        __syncthreads();
    }
    int p = lds[tid] - s;  // exclusive prefix of this thread within block
    p += a0; if (base + 0 < N) rowptr[base + 1] = p;
    p += a1; if (base + 1 < N) rowptr[base + 2] = p;
    p += a2; if (base + 2 < N) rowptr[base + 3] = p;
    p += a3; if (base + 3 < N) rowptr[base + 4] = p;
    if (tid == 255) part[blockIdx.x] = lds[255];
}

// scan step 2: single block, exclusive scan over up to 1024 block sums (in place)
__global__ void gin_scan2(int* __restrict__ part, int NB) {
    __shared__ int lds[256];
    int tid = threadIdx.x;
    int base = tid * 4;
    int a0 = (base + 0 < NB) ? part[base + 0] : 0;
    int a1 = (base + 1 < NB) ? part[base + 1] : 0;
    int a2 = (base + 2 < NB) ? part[base + 2] : 0;
    int a3 = (base + 3 < NB) ? part[base + 3] : 0;
    int s = a0 + a1 + a2 + a3;
    lds[tid] = s;
    __syncthreads();
    for (int off = 1; off < 256; off <<= 1) {
        int v = (tid >= off) ? lds[tid - off] : 0;
        __syncthreads();
        lds[tid] += v;
        __syncthreads();
    }
    int p = lds[tid] - s;  // exclusive prefix
    if (base + 0 < NB) { int t = part[base + 0]; part[base + 0] = p; p += t; }
    if (base + 1 < NB) { int t = part[base + 1]; part[base + 1] = p; p += t; }
    if (base + 2 < NB) { int t = part[base + 2]; part[base + 2] = p; p += t; }
    if (base + 3 < NB) { int t = part[base + 3]; part[base + 3] = p; p += t; }
}

// scan step 3: add block offsets; set rowptr[0]=0
__global__ void gin_scan3(int* __restrict__ rowptr, const int* __restrict__ part, int N) {
    int i = blockIdx.x * blockDim.x + threadIdx.x;
    if (i < N) rowptr[i + 1] += part[i >> 10];
    if (i == 0) rowptr[0] = 0;
}

// fill adjacency: adj[rowptr[dst]+k] = src (cursor = zeroed deg buffer, reused)
__global__ void gin_fill(const int* __restrict__ src, const int* __restrict__ dst,
                         const int* __restrict__ rowptr, int* __restrict__ cursor,
                         int* __restrict__ adj, int E) {
    int e = blockIdx.x * blockDim.x + threadIdx.x;
    if (e < E) {
        int d = dst[e];
        int pos = atomicAdd(&cursor[d], 1);
        adj[rowptr[d] + pos] = src[e];
    }
}

// ======================= per-layer kernels =======================

// gather with folded BN of the previous layer:
// out[i] = scale*(h[i] + sum_{j->i} h[j]) + (1+deg_i)*shift
// (scale=1,shift=0 for layer 1). One wave per node, lane = channel.
__global__ void gin_gather(const float* __restrict__ hin, float* __restrict__ out,
                           const int* __restrict__ rowptr, const int* __restrict__ adj,
                           const float* __restrict__ ss, int N) {
    int t = blockIdx.x * blockDim.x + threadIdx.x;
    int lane = t & 63;
    int gwid = t >> 6;
    int nw = (gridDim.x * blockDim.x) >> 6;
    float scale = ss[lane], shift = ss[DIM + lane];
    for (int row = gwid; row < N; row += nw) {
        int rb = rowptr[row], re = rowptr[row + 1];
        float v = hin[row * DIM + lane];
        int j = rb;
        for (; j + 1 < re; j += 2) {
            int s0 = adj[j], s1 = adj[j + 1];
            v += hin[s0 * DIM + lane];
            v += hin[s1 * DIM + lane];
        }
        if (j < re) v += hin[adj[j] * DIM + lane];
        out[row * DIM + lane] = scale * v + (float)(re - rb + 1) * shift;
    }
}

// fused MLP: out = relu(relu(in@Wa+Ba)@Wb+Bb), accumulate BN stats.
// 2 rows per wave to halve LDS weight-broadcast traffic.
__global__ void __launch_bounds__(256, 4)
gin_mlp(const float* __restrict__ in, float* __restrict__ out,
        const float* __restrict__ Wa, const float* __restrict__ Ba,
        const float* __restrict__ Wb, const float* __restrict__ Bb,
        float* __restrict__ stats, int N) {
    __shared__ float sWa[DIM * DIM];
    __shared__ float sWb[DIM * DIM];
    __shared__ float sBa[DIM], sBb[DIM];
    __shared__ float sstat[4 * 2 * DIM];
    int tid = threadIdx.x;
    for (int i = tid; i < DIM * DIM; i += blockDim.x) { sWa[i] = Wa[i]; sWb[i] = Wb[i]; }
    if (tid < DIM) { sBa[tid] = Ba[tid]; sBb[tid] = Bb[tid]; }
    __syncthreads();

    int lane = tid & 63, wid = tid >> 6;
    int gwid = (blockIdx.x * blockDim.x + tid) >> 6;
    int nw = (gridDim.x * blockDim.x) >> 6;

    float s = 0.f, sq = 0.f;
    for (int p = gwid; 2 * p < N; p += nw) {
        int row = 2 * p;
        bool two = (row + 1 < N);
        float v0 = in[row * DIM + lane];
        float v1 = two ? in[(row + 1) * DIM + lane] : 0.f;
        float t0 = sBa[lane], t1 = t0;
        #pragma unroll
        for (int k = 0; k < DIM; k++) {
            float w = sWa[k * DIM + lane];
            t0 = fmaf(__shfl(v0, k), w, t0);
            t1 = fmaf(__shfl(v1, k), w, t1);
        }
        t0 = fmaxf(t0, 0.f); t1 = fmaxf(t1, 0.f);
        float u0 = sBb[lane], u1 = u0;
        #pragma unroll
        for (int k = 0; k < DIM; k++) {
            float w = sWb[k * DIM + lane];
            u0 = fmaf(__shfl(t0, k), w, u0);
            u1 = fmaf(__shfl(t1, k), w, u1);
        }
        u0 = fmaxf(u0, 0.f);
        out[row * DIM + lane] = u0;
        s += u0; sq += u0 * u0;
        if (two) {
            u1 = fmaxf(u1, 0.f);
            out[(row + 1) * DIM + lane] = u1;
            s += u1; sq += u1 * u1;
        }
    }
    sstat[wid * 2 * DIM + lane] = s;
    sstat[wid * 2 * DIM + DIM + lane] = sq;
    __syncthreads();
    if (tid < 2 * DIM) {
        float a = sstat[tid] + sstat[2 * DIM + tid] + sstat[4 * DIM + tid] + sstat[6 * DIM + tid];
        atomicAdd(&stats[tid], a);
    }
}

// scale/shift from BN stats: scale=gamma*rsqrt(var+eps), shift=beta-scale*m
__global__ void gin_ss(const float* __restrict__ stats, const float* __restrict__ gamma,
                       const float* __restrict__ beta, float* __restrict__ ss, float invN) {
    int d = threadIdx.x;
    if (d < DIM) {
        float m = stats[d] * invN;
        float var = stats[DIM + d] * invN - m * m;
        float sc = gamma[d] * rsqrtf(var + BN_EPS);
        ss[d] = sc;
        ss[DIM + d] = beta[d] - sc * m;
    }
}

__global__ void gin_ss_init(float* __restrict__ ss) {
    int t = threadIdx.x;  // 128 threads
    ss[t] = (t < DIM) ? 1.f : 0.f;
}

// pool with folded BN3: one wave per graph (batch sorted -> binary search range),
// direct write to d_out with dtype cast. No atomics.
__global__ void gin_pool(const float* __restrict__ h, const int* __restrict__ batch,
                         const float* __restrict__ ss, void* __restrict__ out,
                         int N, int G, const int* __restrict__ flag) {
    int gw = (blockIdx.x * blockDim.x + threadIdx.x) >> 6;
    int lane = threadIdx.x & 63;
    if (gw >= G) return;
    int lo = 0, hi = N;
    while (lo < hi) { int mid = (lo + hi) >> 1; if (batch[mid] < gw) lo = mid + 1; else hi = mid; }
    int s0 = lo;
    hi = N;
    while (lo < hi) { int mid = (lo + hi) >> 1; if (batch[mid] < gw + 1) lo = mid + 1; else hi = mid; }
    int s1 = lo;
    float a0 = 0.f, a1 = 0.f, a2 = 0.f, a3 = 0.f;
    int n = s0;
    for (; n + 3 < s1; n += 4) {
        a0 += h[n * DIM + lane];
        a1 += h[(n + 1) * DIM + lane];
        a2 += h[(n + 2) * DIM + lane];
        a3 += h[(n + 3) * DIM + lane];
    }
    for (; n < s1; n++) a0 += h[n * DIM + lane];
    float acc = (a0 + a1) + (a2 + a3);
    float v = ss[lane] * acc + (float)(s1 - s0) * ss[DIM + lane];
    int f = flag[0];
    if (f) ((bf16*)out)[gw * DIM + lane] = __float2bfloat16(v);
    else   ((float*)out)[gw * DIM + lane] = v;
}

extern "C" void kernel_launch(void* const* d_in, const int* in_sizes, int n_in,
                              void* d_out, int out_size, void* d_ws, size_t ws_size,
                              hipStream_t stream) {
    (void)hipGetLastError();  // clear any stale error

    const int N = in_sizes[0] / DIM;   // F_IN == DIM == 64
    const int E = in_sizes[1] / 2;
    const int G = out_size / DIM;
    const size_t ND = (size_t)N * DIM;

    const void* x     = d_in[0];
    const int*  ei    = (const int*)d_in[1];
    const int*  srcp  = ei;
    const int*  dstp  = ei + E;
    const int*  batch = (const int*)d_in[2];

    // workspace layout
    int*   flag   = (int*)d_ws;
    float* P      = (float*)d_ws + 64;         // staged f32 params (25344 used)
    float* bufA   = P + 25600;                 // h
    float* bufB   = bufA + ND;                 // gathered / mid
    float* stats  = bufB + ND;                 // [128]
    float* ss     = stats + 128;               // [128] scale|shift
    int*   rowptr = (int*)(ss + 128);          // [N+1]
    int*   deg    = rowptr + (N + 1);          // [N] (reused as fill cursor)
    int*   part   = deg + N;                   // [1024]
    int*   adj    = part + 1024;               // [E]
    size_t need = ((size_t)64 + 25600 + 2 * ND + 256) * sizeof(float)
                + ((size_t)(N + 1) + N + 1024 + E) * sizeof(int);
    if (ws_size < need) {  // "workspace too small" marker: err prints ~5e33
        hipMemsetAsync(d_out, 0x77, (size_t)out_size * 2, stream);
        return;
    }

    // param staging pack: per layer {wa, ba, wb, bb, gamma, beta}
    ParamPack pk;
    int off = 0;
    for (int l = 0; l < 3; l++) {
        for (int j = 0; j < 6; j++) {
            int idx = 3 + 6 * l + j;
            pk.p[6 * l + j]   = d_in[idx];
            pk.n[6 * l + j]   = in_sizes[idx];
            pk.off[6 * l + j] = off;
            off += in_sizes[idx];
        }
    }
    float* wa[3], *ba[3], *wb[3], *bb[3], *gm[3], *be[3];
    for (int l = 0; l < 3; l++) {
        float* base = P + l * 8448;
        wa[l] = base;        ba[l] = base + 4096;
        wb[l] = base + 4160; bb[l] = base + 8256;
        gm[l] = base + 8320; be[l] = base + 8384;
    }

    const int TB = 256;
    const int grid_nd = (int)((ND + TB - 1) / TB);
    const int grid_n  = (N + TB - 1) / TB;
    const int grid_e  = (E + TB - 1) / TB;
    const int grid_g  = (G * DIM + TB - 1) / TB;
    const int NB      = (N + 1023) / 1024;

    gin_detect<<<1, 256, 0, stream>>>(d_in[3], in_sizes[3], flag);
    gin_cvt_params<<<18, 256, 0, stream>>>(pk, P, flag);
    GINEncoder_16114717295311_kernel<<<grid_nd, TB, 0, stream>>>(x, bufA, (int)ND, flag);

    // CSR build (once; reused by all 3 layers)
    gin_zero<<<grid_n, TB, 0, stream>>>((float*)deg, N);
    gin_hist<<<grid_e, TB, 0, stream>>>(dstp, deg, E);
    gin_scan1<<<NB, 256, 0, stream>>>(deg, rowptr, part, N);
    gin_scan2<<<1, 256, 0, stream>>>(part, NB);
    gin_scan3<<<grid_n, TB, 0, stream>>>(rowptr, part, N);
    gin_zero<<<grid_n, TB, 0, stream>>>((float*)deg, N);  // deg -> cursor
    gin_fill<<<grid_e, TB, 0, stream>>>(srcp, dstp, rowptr, deg, adj, E);

    gin_ss_init<<<1, 128, 0, stream>>>(ss);
    for (int l = 0; l < 3; l++) {
        gin_gather<<<2048, TB, 0, stream>>>(bufA, bufB, rowptr, adj, ss, N);
        gin_zero<<<1, 128, 0, stream>>>(stats, 128);
        gin_mlp<<<1024, TB, 0, stream>>>(bufB, bufA, wa[l], ba[l], wb[l], bb[l], stats, N);
        gin_ss<<<1, 64, 0, stream>>>(stats, gm[l], be[l], ss, 1.0f / (float)N);
    }

    gin_pool<<<grid_g, TB, 0, stream>>>(bufA, batch, ss, d_out, N, G, flag);

    // "some launch failed" marker: err prints ~1.7e38 (bf16) / 3.4e38 (f32)
    hipError_t e = hipGetLastError();
    if (e != hipSuccess) {
        hipMemsetAsync(d_out, 0x7F, (size_t)out_size * 2, stream);
    }
}

// Round 2
// 1502.023 us; speedup vs baseline: 1.3762x; 1.3762x over previous
//
#include <hip/hip_runtime.h>
#include <hip/hip_bf16.h>

typedef __hip_bfloat16 bf16;

#define DIM 64
#define BN_EPS 1e-5f

struct ParamPack {
    const void* p[18];
    int n[18];
    int off[18];
};

// ---- read element i of p as float, interpreting per flag (1=bf16, 0=f32) ----
__device__ __forceinline__ float load_as(const void* p, int i, int isbf16) {
    if (isbf16) {
        unsigned short b = ((const unsigned short*)p)[i];
        unsigned int u = ((unsigned int)b) << 16;
        return __uint_as_float(u);
    }
    return ((const float*)p)[i];
}

// ---- dtype detect: scan w1a (values uniform in +-0.125). bf16 interp of real
// bf16 data passes ~100%; bf16 interp of f32 bits passes ~55%. ----
__global__ void gin_detect(const void* w, int nelem, int* flag) {
    const unsigned short* u = (const unsigned short*)w;
    int tid = threadIdx.x;
    int cnt = 0;
    for (int i = tid; i < nelem; i += blockDim.x) {
        unsigned int f = ((unsigned int)u[i]) << 16;
        float v = __uint_as_float(f);
        float av = fabsf(v);
        if (av <= 0.126f && (av == 0.0f || av >= 1e-8f)) cnt++;
    }
    __shared__ int sc[256];
    sc[tid] = cnt;
    __syncthreads();
    for (int s = 128; s > 0; s >>= 1) {
        if (tid < s) sc[tid] += sc[tid + s];
        __syncthreads();
    }
    if (tid == 0) flag[0] = (sc[0] * 10 >= nelem * 9) ? 1 : 0;
}

// ---- stage all 18 param tensors into f32 workspace ----
__global__ void gin_cvt_params(ParamPack pk, float* __restrict__ out,
                               const int* __restrict__ flag) {
    int b = blockIdx.x;
    int f = flag[0];
    const void* p = pk.p[b];
    float* o = out + pk.off[b];
    int n = pk.n[b];
    for (int i = threadIdx.x; i < n; i += blockDim.x) o[i] = load_as(p, i, f);
}

// ---- x -> f32 (named with problem identifier) ----
__global__ void GINEncoder_16114717295311_kernel(const void* __restrict__ x,
                                                 float* __restrict__ h, int n,
                                                 const int* __restrict__ flag) {
    int i = blockIdx.x * blockDim.x + threadIdx.x;
    int f = flag[0];
    if (i < n) h[i] = load_as(x, i, f);
}

__global__ void gin_zero(float* __restrict__ p, int n) {
    int i = blockIdx.x * blockDim.x + threadIdx.x;
    if (i < n) p[i] = 0.0f;
}

// ======================= CSR build (once; graph reused 3x) =======================

// in-degree histogram keyed by dst
__global__ void gin_hist(const int* __restrict__ dst, int* __restrict__ deg, int E) {
    int e = blockIdx.x * blockDim.x + threadIdx.x;
    if (e < E) atomicAdd(&deg[dst[e]], 1);
}

// scan step 1: per-1024-block inclusive scan of deg -> rowptr[i+1]; block sums -> part
__global__ void gin_scan1(const int* __restrict__ deg, int* __restrict__ rowptr,
                          int* __restrict__ part, int N) {
    __shared__ int lds[256];
    int tid = threadIdx.x;
    int base = blockIdx.x * 1024 + tid * 4;
    int a0 = (base + 0 < N) ? deg[base + 0] : 0;
    int a1 = (base + 1 < N) ? deg[base + 1] : 0;
    int a2 = (base + 2 < N) ? deg[base + 2] : 0;
    int a3 = (base + 3 < N) ? deg[base + 3] : 0;
    int s = a0 + a1 + a2 + a3;
    lds[tid] = s;
    __syncthreads();
    for (int off = 1; off < 256; off <<= 1) {
        int v = (tid >= off) ? lds[tid - off] : 0;
        __syncthreads();
        lds[tid] += v;
        __syncthreads();
    }
    int p = lds[tid] - s;  // exclusive prefix of this thread within block
    p += a0; if (base + 0 < N) rowptr[base + 1] = p;
    p += a1; if (base + 1 < N) rowptr[base + 2] = p;
    p += a2; if (base + 2 < N) rowptr[base + 3] = p;
    p += a3; if (base + 3 < N) rowptr[base + 4] = p;
    if (tid == 255) part[blockIdx.x] = lds[255];
}

// scan step 2: single block, exclusive scan over up to 1024 block sums (in place)
__global__ void gin_scan2(int* __restrict__ part, int NB) {
    __shared__ int lds[256];
    int tid = threadIdx.x;
    int base = tid * 4;
    int a0 = (base + 0 < NB) ? part[base + 0] : 0;
    int a1 = (base + 1 < NB) ? part[base + 1] : 0;
    int a2 = (base + 2 < NB) ? part[base + 2] : 0;
    int a3 = (base + 3 < NB) ? part[base + 3] : 0;
    int s = a0 + a1 + a2 + a3;
    lds[tid] = s;
    __syncthreads();
    for (int off = 1; off < 256; off <<= 1) {
        int v = (tid >= off) ? lds[tid - off] : 0;
        __syncthreads();
        lds[tid] += v;
        __syncthreads();
    }
    int p = lds[tid] - s;  // exclusive prefix
    if (base + 0 < NB) { int t = part[base + 0]; part[base + 0] = p; p += t; }
    if (base + 1 < NB) { int t = part[base + 1]; part[base + 1] = p; p += t; }
    if (base + 2 < NB) { int t = part[base + 2]; part[base + 2] = p; p += t; }
    if (base + 3 < NB) { int t = part[base + 3]; part[base + 3] = p; p += t; }
}

// scan step 3: add block offsets; set rowptr[0]=0
__global__ void gin_scan3(int* __restrict__ rowptr, const int* __restrict__ part, int N) {
    int i = blockIdx.x * blockDim.x + threadIdx.x;
    if (i < N) rowptr[i + 1] += part[i >> 10];
    if (i == 0) rowptr[0] = 0;
}

// fill adjacency: adj[rowptr[dst]+k] = src (cursor = zeroed deg buffer, reused)
__global__ void gin_fill(const int* __restrict__ src, const int* __restrict__ dst,
                         const int* __restrict__ rowptr, int* __restrict__ cursor,
                         int* __restrict__ adj, int E) {
    int e = blockIdx.x * blockDim.x + threadIdx.x;
    if (e < E) {
        int d = dst[e];
        int pos = atomicAdd(&cursor[d], 1);
        adj[rowptr[d] + pos] = src[e];
    }
}

// ======================= per-layer kernels =======================

// gather with folded BN of the previous layer:
// out[i] = scale*(h[i] + sum_{j->i} h[j]) + (1+deg_i)*shift
// (scale=1,shift=0 for layer 1). One wave per node, lane = channel.
// adj[j] is wave-uniform -> scalar loads; unroll 4 for outstanding vector loads.
__global__ void gin_gather(const float* __restrict__ hin, float* __restrict__ out,
                           const int* __restrict__ rowptr, const int* __restrict__ adj,
                           const float* __restrict__ ss, int N) {
    int t = blockIdx.x * blockDim.x + threadIdx.x;
    int lane = t & 63;
    int gwid = t >> 6;
    int nw = (gridDim.x * blockDim.x) >> 6;
    float scale = ss[lane], shift = ss[DIM + lane];
    for (int row = gwid; row < N; row += nw) {
        int rb = rowptr[row], re = rowptr[row + 1];
        float v = hin[row * DIM + lane];
        int j = rb;
        for (; j + 3 < re; j += 4) {
            int s0 = adj[j], s1 = adj[j + 1], s2 = adj[j + 2], s3 = adj[j + 3];
            float f0 = hin[s0 * DIM + lane];
            float f1 = hin[s1 * DIM + lane];
            float f2 = hin[s2 * DIM + lane];
            float f3 = hin[s3 * DIM + lane];
            v += (f0 + f1) + (f2 + f3);
        }
        for (; j < re; j++) v += hin[adj[j] * DIM + lane];
        out[row * DIM + lane] = scale * v + (float)(re - rb + 1) * shift;
    }
}

// fused MLP: out = relu(relu(in@Wa+Ba)@Wb+Bb), accumulate BN stats.
// ONE row per wave (round-0 structure): ~40 live VGPRs, no spill.
// NO __launch_bounds__ -- round 1's (256,4) + 2-row body forced VGPR=64 and
// spilled ~35 KB/iteration to scratch (FETCH 1.4 GB, 504 us).
__global__ void gin_mlp(const float* __restrict__ in, float* __restrict__ out,
                        const float* __restrict__ Wa, const float* __restrict__ Ba,
                        const float* __restrict__ Wb, const float* __restrict__ Bb,
                        float* __restrict__ stats, int N) {
    __shared__ float sWa[DIM * DIM];
    __shared__ float sWb[DIM * DIM];
    __shared__ float sBa[DIM], sBb[DIM];
    __shared__ float sstat[4 * 2 * DIM];
    int tid = threadIdx.x;
    for (int i = tid; i < DIM * DIM; i += blockDim.x) { sWa[i] = Wa[i]; sWb[i] = Wb[i]; }
    if (tid < DIM) { sBa[tid] = Ba[tid]; sBb[tid] = Bb[tid]; }
    __syncthreads();

    int lane = tid & 63, wid = tid >> 6;
    int gwid = (blockIdx.x * blockDim.x + tid) >> 6;
    int nw = (gridDim.x * blockDim.x) >> 6;

    float s = 0.f, sq = 0.f;
    for (int row = gwid; row < N; row += nw) {
        float v = in[row * DIM + lane];
        float t = sBa[lane];
        #pragma unroll
        for (int k = 0; k < DIM; k++)
            t = fmaf(__shfl(v, k), sWa[k * DIM + lane], t);
        t = fmaxf(t, 0.f);
        float u = sBb[lane];
        #pragma unroll
        for (int k = 0; k < DIM; k++)
            u = fmaf(__shfl(t, k), sWb[k * DIM + lane], u);
        u = fmaxf(u, 0.f);
        out[row * DIM + lane] = u;
        s += u; sq += u * u;
    }
    sstat[wid * 2 * DIM + lane] = s;
    sstat[wid * 2 * DIM + DIM + lane] = sq;
    __syncthreads();
    if (tid < 2 * DIM) {
        float a = sstat[tid] + sstat[2 * DIM + tid] + sstat[4 * DIM + tid] + sstat[6 * DIM + tid];
        atomicAdd(&stats[tid], a);
    }
}

// scale/shift from BN stats: scale=gamma*rsqrt(var+eps), shift=beta-scale*m
__global__ void gin_ss(const float* __restrict__ stats, const float* __restrict__ gamma,
                       const float* __restrict__ beta, float* __restrict__ ss, float invN) {
    int d = threadIdx.x;
    if (d < DIM) {
        float m = stats[d] * invN;
        float var = stats[DIM + d] * invN - m * m;
        float sc = gamma[d] * rsqrtf(var + BN_EPS);
        ss[d] = sc;
        ss[DIM + d] = beta[d] - sc * m;
    }
}

__global__ void gin_ss_init(float* __restrict__ ss) {
    int t = threadIdx.x;  // 128 threads
    ss[t] = (t < DIM) ? 1.f : 0.f;
}

// pool with folded BN3: one wave per graph (batch sorted -> binary search range),
// direct write to d_out with dtype cast. No atomics.
__global__ void gin_pool(const float* __restrict__ h, const int* __restrict__ batch,
                         const float* __restrict__ ss, void* __restrict__ out,
                         int N, int G, const int* __restrict__ flag) {
    int gw = (blockIdx.x * blockDim.x + threadIdx.x) >> 6;
    int lane = threadIdx.x & 63;
    if (gw >= G) return;
    int lo = 0, hi = N;
    while (lo < hi) { int mid = (lo + hi) >> 1; if (batch[mid] < gw) lo = mid + 1; else hi = mid; }
    int s0 = lo;
    hi = N;
    while (lo < hi) { int mid = (lo + hi) >> 1; if (batch[mid] < gw + 1) lo = mid + 1; else hi = mid; }
    int s1 = lo;
    float a0 = 0.f, a1 = 0.f, a2 = 0.f, a3 = 0.f;
    int n = s0;
    for (; n + 3 < s1; n += 4) {
        a0 += h[n * DIM + lane];
        a1 += h[(n + 1) * DIM + lane];
        a2 += h[(n + 2) * DIM + lane];
        a3 += h[(n + 3) * DIM + lane];
    }
    for (; n < s1; n++) a0 += h[n * DIM + lane];
    float acc = (a0 + a1) + (a2 + a3);
    float v = ss[lane] * acc + (float)(s1 - s0) * ss[DIM + lane];
    int f = flag[0];
    if (f) ((bf16*)out)[gw * DIM + lane] = __float2bfloat16(v);
    else   ((float*)out)[gw * DIM + lane] = v;
}

extern "C" void kernel_launch(void* const* d_in, const int* in_sizes, int n_in,
                              void* d_out, int out_size, void* d_ws, size_t ws_size,
                              hipStream_t stream) {
    (void)hipGetLastError();  // clear any stale error

    const int N = in_sizes[0] / DIM;   // F_IN == DIM == 64
    const int E = in_sizes[1] / 2;
    const int G = out_size / DIM;
    const size_t ND = (size_t)N * DIM;

    const void* x     = d_in[0];
    const int*  ei    = (const int*)d_in[1];
    const int*  srcp  = ei;
    const int*  dstp  = ei + E;
    const int*  batch = (const int*)d_in[2];

    // workspace layout
    int*   flag   = (int*)d_ws;
    float* P      = (float*)d_ws + 64;         // staged f32 params (25344 used)
    float* bufA   = P + 25600;                 // h
    float* bufB   = bufA + ND;                 // gathered / mid
    float* stats  = bufB + ND;                 // [128]
    float* ss     = stats + 128;               // [128] scale|shift
    int*   rowptr = (int*)(ss + 128);          // [N+1]
    int*   deg    = rowptr + (N + 1);          // [N] (reused as fill cursor)
    int*   part   = deg + N;                   // [1024]
    int*   adj    = part + 1024;               // [E]
    size_t need = ((size_t)64 + 25600 + 2 * ND + 256) * sizeof(float)
                + ((size_t)(N + 1) + N + 1024 + E) * sizeof(int);
    if (ws_size < need) {  // "workspace too small" marker: err prints ~5e33
        hipMemsetAsync(d_out, 0x77, (size_t)out_size * 2, stream);
        return;
    }

    // param staging pack: per layer {wa, ba, wb, bb, gamma, beta}
    ParamPack pk;
    int off = 0;
    for (int l = 0; l < 3; l++) {
        for (int j = 0; j < 6; j++) {
            int idx = 3 + 6 * l + j;
            pk.p[6 * l + j]   = d_in[idx];
            pk.n[6 * l + j]   = in_sizes[idx];
            pk.off[6 * l + j] = off;
            off += in_sizes[idx];
        }
    }
    float* wa[3], *ba[3], *wb[3], *bb[3], *gm[3], *be[3];
    for (int l = 0; l < 3; l++) {
        float* base = P + l * 8448;
        wa[l] = base;        ba[l] = base + 4096;
        wb[l] = base + 4160; bb[l] = base + 8256;
        gm[l] = base + 8320; be[l] = base + 8384;
    }

    const int TB = 256;
    const int grid_nd = (int)((ND + TB - 1) / TB);
    const int grid_n  = (N + TB - 1) / TB;
    const int grid_e  = (E + TB - 1) / TB;
    const int grid_g  = (G * DIM + TB - 1) / TB;
    const int NB      = (N + 1023) / 1024;

    gin_detect<<<1, 256, 0, stream>>>(d_in[3], in_sizes[3], flag);
    gin_cvt_params<<<18, 256, 0, stream>>>(pk, P, flag);
    GINEncoder_16114717295311_kernel<<<grid_nd, TB, 0, stream>>>(x, bufA, (int)ND, flag);

    // CSR build (once; reused by all 3 layers)
    gin_zero<<<grid_n, TB, 0, stream>>>((float*)deg, N);
    gin_hist<<<grid_e, TB, 0, stream>>>(dstp, deg, E);
    gin_scan1<<<NB, 256, 0, stream>>>(deg, rowptr, part, N);
    gin_scan2<<<1, 256, 0, stream>>>(part, NB);
    gin_scan3<<<grid_n, TB, 0, stream>>>(rowptr, part, N);
    gin_zero<<<grid_n, TB, 0, stream>>>((float*)deg, N);  // deg -> cursor
    gin_fill<<<grid_e, TB, 0, stream>>>(srcp, dstp, rowptr, deg, adj, E);

    gin_ss_init<<<1, 128, 0, stream>>>(ss);
    for (int l = 0; l < 3; l++) {
        gin_gather<<<2048, TB, 0, stream>>>(bufA, bufB, rowptr, adj, ss, N);
        gin_zero<<<1, 128, 0, stream>>>(stats, 128);
        gin_mlp<<<1024, TB, 0, stream>>>(bufB, bufA, wa[l], ba[l], wb[l], bb[l], stats, N);
        gin_ss<<<1, 64, 0, stream>>>(stats, gm[l], be[l], ss, 1.0f / (float)N);
    }

    gin_pool<<<grid_g, TB, 0, stream>>>(bufA, batch, ss, d_out, N, G, flag);

    // "some launch failed" marker: err prints ~1.7e38 (bf16) / 3.4e38 (f32)
    hipError_t e = hipGetLastError();
    if (e != hipSuccess) {
        hipMemsetAsync(d_out, 0x7F, (size_t)out_size * 2, stream);
    }
}

// Round 3
// 704.837 us; speedup vs baseline: 2.9327x; 2.1310x over previous
//
#include <hip/hip_runtime.h>
#include <hip/hip_bf16.h>

typedef __hip_bfloat16 bf16;

#define DIM 64
#define BN_EPS 1e-5f

struct ParamPack {
    const void* p[18];
    int n[18];
    int off[18];
};

// ---- read element i of p as float, interpreting per flag (1=bf16, 0=f32) ----
__device__ __forceinline__ float load_as(const void* p, int i, int isbf16) {
    if (isbf16) {
        unsigned short b = ((const unsigned short*)p)[i];
        unsigned int u = ((unsigned int)b) << 16;
        return __uint_as_float(u);
    }
    return ((const float*)p)[i];
}

// ---- dtype detect: scan w1a (values uniform in +-0.125). bf16 interp of real
// bf16 data passes ~100%; bf16 interp of f32 bits passes ~55%. ----
__global__ void gin_detect(const void* w, int nelem, int* flag) {
    const unsigned short* u = (const unsigned short*)w;
    int tid = threadIdx.x;
    int cnt = 0;
    for (int i = tid; i < nelem; i += blockDim.x) {
        unsigned int f = ((unsigned int)u[i]) << 16;
        float v = __uint_as_float(f);
        float av = fabsf(v);
        if (av <= 0.126f && (av == 0.0f || av >= 1e-8f)) cnt++;
    }
    __shared__ int sc[256];
    sc[tid] = cnt;
    __syncthreads();
    for (int s = 128; s > 0; s >>= 1) {
        if (tid < s) sc[tid] += sc[tid + s];
        __syncthreads();
    }
    if (tid == 0) flag[0] = (sc[0] * 10 >= nelem * 9) ? 1 : 0;
}

// ---- stage all 18 param tensors into f32 workspace ----
__global__ void gin_cvt_params(ParamPack pk, float* __restrict__ out,
                               const int* __restrict__ flag) {
    int b = blockIdx.x;
    int f = flag[0];
    const void* p = pk.p[b];
    float* o = out + pk.off[b];
    int n = pk.n[b];
    for (int i = threadIdx.x; i < n; i += blockDim.x) o[i] = load_as(p, i, f);
}

// ---- x -> f32 (named with problem identifier) ----
__global__ void GINEncoder_16114717295311_kernel(const void* __restrict__ x,
                                                 float* __restrict__ h, int n,
                                                 const int* __restrict__ flag) {
    int i = blockIdx.x * blockDim.x + threadIdx.x;
    int f = flag[0];
    if (i < n) h[i] = load_as(x, i, f);
}

__global__ void gin_zero(float* __restrict__ p, int n) {
    int i = blockIdx.x * blockDim.x + threadIdx.x;
    if (i < n) p[i] = 0.0f;
}

// ======================= CSR build (once; graph reused 3x) =======================

// in-degree histogram keyed by dst
__global__ void gin_hist(const int* __restrict__ dst, int* __restrict__ deg, int E) {
    int e = blockIdx.x * blockDim.x + threadIdx.x;
    if (e < E) atomicAdd(&deg[dst[e]], 1);
}

// scan step 1: per-1024-block inclusive scan of deg -> rowptr[i+1]; block sums -> part
__global__ void gin_scan1(const int* __restrict__ deg, int* __restrict__ rowptr,
                          int* __restrict__ part, int N) {
    __shared__ int lds[256];
    int tid = threadIdx.x;
    int base = blockIdx.x * 1024 + tid * 4;
    int a0 = (base + 0 < N) ? deg[base + 0] : 0;
    int a1 = (base + 1 < N) ? deg[base + 1] : 0;
    int a2 = (base + 2 < N) ? deg[base + 2] : 0;
    int a3 = (base + 3 < N) ? deg[base + 3] : 0;
    int s = a0 + a1 + a2 + a3;
    lds[tid] = s;
    __syncthreads();
    for (int off = 1; off < 256; off <<= 1) {
        int v = (tid >= off) ? lds[tid - off] : 0;
        __syncthreads();
        lds[tid] += v;
        __syncthreads();
    }
    int p = lds[tid] - s;  // exclusive prefix of this thread within block
    p += a0; if (base + 0 < N) rowptr[base + 1] = p;
    p += a1; if (base + 1 < N) rowptr[base + 2] = p;
    p += a2; if (base + 2 < N) rowptr[base + 3] = p;
    p += a3; if (base + 3 < N) rowptr[base + 4] = p;
    if (tid == 255) part[blockIdx.x] = lds[255];
}

// scan step 2: single block, exclusive scan over up to 1024 block sums (in place)
__global__ void gin_scan2(int* __restrict__ part, int NB) {
    __shared__ int lds[256];
    int tid = threadIdx.x;
    int base = tid * 4;
    int a0 = (base + 0 < NB) ? part[base + 0] : 0;
    int a1 = (base + 1 < NB) ? part[base + 1] : 0;
    int a2 = (base + 2 < NB) ? part[base + 2] : 0;
    int a3 = (base + 3 < NB) ? part[base + 3] : 0;
    int s = a0 + a1 + a2 + a3;
    lds[tid] = s;
    __syncthreads();
    for (int off = 1; off < 256; off <<= 1) {
        int v = (tid >= off) ? lds[tid - off] : 0;
        __syncthreads();
        lds[tid] += v;
        __syncthreads();
    }
    int p = lds[tid] - s;  // exclusive prefix
    if (base + 0 < NB) { int t = part[base + 0]; part[base + 0] = p; p += t; }
    if (base + 1 < NB) { int t = part[base + 1]; part[base + 1] = p; p += t; }
    if (base + 2 < NB) { int t = part[base + 2]; part[base + 2] = p; p += t; }
    if (base + 3 < NB) { int t = part[base + 3]; part[base + 3] = p; p += t; }
}

// scan step 3: add block offsets; set rowptr[0]=0
__global__ void gin_scan3(int* __restrict__ rowptr, const int* __restrict__ part, int N) {
    int i = blockIdx.x * blockDim.x + threadIdx.x;
    if (i < N) rowptr[i + 1] += part[i >> 10];
    if (i == 0) rowptr[0] = 0;
}

// fill adjacency: adj[rowptr[dst]+k] = src (cursor = zeroed deg buffer, reused)
__global__ void gin_fill(const int* __restrict__ src, const int* __restrict__ dst,
                         const int* __restrict__ rowptr, int* __restrict__ cursor,
                         int* __restrict__ adj, int E) {
    int e = blockIdx.x * blockDim.x + threadIdx.x;
    if (e < E) {
        int d = dst[e];
        int pos = atomicAdd(&cursor[d], 1);
        adj[rowptr[d] + pos] = src[e];
    }
}

// ======================= per-layer kernels =======================

// gather with folded BN of the previous layer:
// out[i] = scale*(h[i] + sum_{j->i} h[j]) + (1+deg_i)*shift
// (scale=1,shift=0 for layer 1). One wave per node, lane = channel.
// adj[j] is wave-uniform -> scalar loads; unroll 8 for outstanding vector loads.
__global__ void gin_gather(const float* __restrict__ hin, float* __restrict__ out,
                           const int* __restrict__ rowptr, const int* __restrict__ adj,
                           const float* __restrict__ ss, int N) {
    int t = blockIdx.x * blockDim.x + threadIdx.x;
    int lane = t & 63;
    int gwid = t >> 6;
    int nw = (gridDim.x * blockDim.x) >> 6;
    float scale = ss[lane], shift = ss[DIM + lane];
    for (int row = gwid; row < N; row += nw) {
        int rb = rowptr[row], re = rowptr[row + 1];
        float v = hin[row * DIM + lane];
        int j = rb;
        for (; j + 7 < re; j += 8) {
            int s0 = adj[j], s1 = adj[j + 1], s2 = adj[j + 2], s3 = adj[j + 3];
            int s4 = adj[j + 4], s5 = adj[j + 5], s6 = adj[j + 6], s7 = adj[j + 7];
            float f0 = hin[s0 * DIM + lane];
            float f1 = hin[s1 * DIM + lane];
            float f2 = hin[s2 * DIM + lane];
            float f3 = hin[s3 * DIM + lane];
            float f4 = hin[s4 * DIM + lane];
            float f5 = hin[s5 * DIM + lane];
            float f6 = hin[s6 * DIM + lane];
            float f7 = hin[s7 * DIM + lane];
            v += ((f0 + f1) + (f2 + f3)) + ((f4 + f5) + (f6 + f7));
        }
        for (; j + 1 < re; j += 2) {
            int s0 = adj[j], s1 = adj[j + 1];
            v += hin[s0 * DIM + lane] + hin[s1 * DIM + lane];
        }
        if (j < re) v += hin[adj[j] * DIM + lane];
        out[row * DIM + lane] = scale * v + (float)(re - rb + 1) * shift;
    }
}

// fused MLP as LDS-tiled register-blocked GEMM pair (NO __shfl -- rounds 1/2
// showed the 64-deep unrolled shfl-broadcast chains spill to scratch and thrash
// L2: FETCH 941 MB vs 30 MB logical, 327 us). 64-row tile/block, 256 threads,
// thread (tx,ty) owns a 4x4 register sub-tile; ~45 live VGPRs, no spill.
// out = relu(relu(in@Wa+Ba)@Wb+Bb), BN stats via shfl_xor+LDS reduction.
__global__ void gin_mlp(const float* __restrict__ in, float* __restrict__ out,
                        const float* __restrict__ Wa, const float* __restrict__ Ba,
                        const float* __restrict__ Wb, const float* __restrict__ Bb,
                        float* __restrict__ stats, int N) {
    __shared__ float sWa[DIM * DIM];
    __shared__ float sWb[DIM * DIM];
    __shared__ float sT[64][DIM + 4];   // +4 pad: rows 16B-aligned, 2-way banks (free)
    __shared__ float sBa[DIM], sBb[DIM];
    __shared__ float sred[4][16][8];

    int tid = threadIdx.x;
    int tx = tid & 15, ty = tid >> 4;
    int rbase = blockIdx.x * 64;

    for (int i = tid; i < DIM * DIM; i += 256) { sWa[i] = Wa[i]; sWb[i] = Wb[i]; }
    if (tid < DIM) { sBa[tid] = Ba[tid]; sBb[tid] = Bb[tid]; }

    // stage input tile (64 rows x 64 cols) as float4, zero-pad invalid rows
    const float4* in4 = (const float4*)in;
    #pragma unroll
    for (int t = 0; t < 4; t++) {
        int e = t * 256 + tid;          // float4 index 0..1023
        int r = e >> 4, c4 = e & 15;
        float4 v = make_float4(0.f, 0.f, 0.f, 0.f);
        if (rbase + r < N) v = in4[(size_t)(rbase + r) * 16 + c4];
        *(float4*)&sT[r][c4 * 4] = v;
    }
    __syncthreads();

    int c0 = tx * 4;
    int r0 = ty * 4;
    float acc[4][4];

    // ---- GEMM1: mid = relu(in @ Wa + Ba) ----
    {
        float4 bia = *(const float4*)&sBa[c0];
        #pragma unroll
        for (int i = 0; i < 4; i++) {
            acc[i][0] = bia.x; acc[i][1] = bia.y; acc[i][2] = bia.z; acc[i][3] = bia.w;
        }
    }
    #pragma unroll 8
    for (int k = 0; k < DIM; k++) {
        float4 b = *(const float4*)&sWa[k * DIM + c0];
        float a0 = sT[r0 + 0][k], a1 = sT[r0 + 1][k];
        float a2 = sT[r0 + 2][k], a3 = sT[r0 + 3][k];
        acc[0][0] = fmaf(a0, b.x, acc[0][0]); acc[0][1] = fmaf(a0, b.y, acc[0][1]);
        acc[0][2] = fmaf(a0, b.z, acc[0][2]); acc[0][3] = fmaf(a0, b.w, acc[0][3]);
        acc[1][0] = fmaf(a1, b.x, acc[1][0]); acc[1][1] = fmaf(a1, b.y, acc[1][1]);
        acc[1][2] = fmaf(a1, b.z, acc[1][2]); acc[1][3] = fmaf(a1, b.w, acc[1][3]);
        acc[2][0] = fmaf(a2, b.x, acc[2][0]); acc[2][1] = fmaf(a2, b.y, acc[2][1]);
        acc[2][2] = fmaf(a2, b.z, acc[2][2]); acc[2][3] = fmaf(a2, b.w, acc[2][3]);
        acc[3][0] = fmaf(a3, b.x, acc[3][0]); acc[3][1] = fmaf(a3, b.y, acc[3][1]);
        acc[3][2] = fmaf(a3, b.z, acc[3][2]); acc[3][3] = fmaf(a3, b.w, acc[3][3]);
    }
    __syncthreads();  // all GEMM1 reads of sT done
    #pragma unroll
    for (int i = 0; i < 4; i++) {
        float4 m;
        m.x = fmaxf(acc[i][0], 0.f); m.y = fmaxf(acc[i][1], 0.f);
        m.z = fmaxf(acc[i][2], 0.f); m.w = fmaxf(acc[i][3], 0.f);
        *(float4*)&sT[r0 + i][c0] = m;
    }
    __syncthreads();

    // ---- GEMM2: out = relu(mid @ Wb + Bb) ----
    {
        float4 bib = *(const float4*)&sBb[c0];
        #pragma unroll
        for (int i = 0; i < 4; i++) {
            acc[i][0] = bib.x; acc[i][1] = bib.y; acc[i][2] = bib.z; acc[i][3] = bib.w;
        }
    }
    #pragma unroll 8
    for (int k = 0; k < DIM; k++) {
        float4 b = *(const float4*)&sWb[k * DIM + c0];
        float a0 = sT[r0 + 0][k], a1 = sT[r0 + 1][k];
        float a2 = sT[r0 + 2][k], a3 = sT[r0 + 3][k];
        acc[0][0] = fmaf(a0, b.x, acc[0][0]); acc[0][1] = fmaf(a0, b.y, acc[0][1]);
        acc[0][2] = fmaf(a0, b.z, acc[0][2]); acc[0][3] = fmaf(a0, b.w, acc[0][3]);
        acc[1][0] = fmaf(a1, b.x, acc[1][0]); acc[1][1] = fmaf(a1, b.y, acc[1][1]);
        acc[1][2] = fmaf(a1, b.z, acc[1][2]); acc[1][3] = fmaf(a1, b.w, acc[1][3]);
        acc[2][0] = fmaf(a2, b.x, acc[2][0]); acc[2][1] = fmaf(a2, b.y, acc[2][1]);
        acc[2][2] = fmaf(a2, b.z, acc[2][2]); acc[2][3] = fmaf(a2, b.w, acc[2][3]);
        acc[3][0] = fmaf(a3, b.x, acc[3][0]); acc[3][1] = fmaf(a3, b.y, acc[3][1]);
        acc[3][2] = fmaf(a3, b.z, acc[3][2]); acc[3][3] = fmaf(a3, b.w, acc[3][3]);
    }

    // relu, store, per-thread BN partials (valid rows only)
    float s[4] = {0.f, 0.f, 0.f, 0.f}, q[4] = {0.f, 0.f, 0.f, 0.f};
    #pragma unroll
    for (int i = 0; i < 4; i++) {
        int r = rbase + r0 + i;
        float4 o;
        o.x = fmaxf(acc[i][0], 0.f); o.y = fmaxf(acc[i][1], 0.f);
        o.z = fmaxf(acc[i][2], 0.f); o.w = fmaxf(acc[i][3], 0.f);
        if (r < N) {
            *(float4*)&out[(size_t)r * DIM + c0] = o;
            s[0] += o.x; q[0] += o.x * o.x;
            s[1] += o.y; q[1] += o.y * o.y;
            s[2] += o.z; q[2] += o.z * o.z;
            s[3] += o.w; q[3] += o.w * o.w;
        }
    }
    // reduce over ty within wave: lanes +16 (ty+1), +32 (ty+2)
    #pragma unroll
    for (int j = 0; j < 4; j++) {
        s[j] += __shfl_xor(s[j], 16); s[j] += __shfl_xor(s[j], 32);
        q[j] += __shfl_xor(q[j], 16); q[j] += __shfl_xor(q[j], 32);
    }
    int wave = tid >> 6, lane = tid & 63;
    if (lane < 16) {
        #pragma unroll
        for (int j = 0; j < 4; j++) {
            sred[wave][lane][j] = s[j];
            sred[wave][lane][4 + j] = q[j];
        }
    }
    __syncthreads();
    if (tid < DIM) {
        int txx = tid >> 2, j = tid & 3;
        float as = sred[0][txx][j] + sred[1][txx][j] + sred[2][txx][j] + sred[3][txx][j];
        float aq = sred[0][txx][4 + j] + sred[1][txx][4 + j] + sred[2][txx][4 + j] + sred[3][txx][4 + j];
        atomicAdd(&stats[tid], as);
        atomicAdd(&stats[DIM + tid], aq);
    }
}

// scale/shift from BN stats: scale=gamma*rsqrt(var+eps), shift=beta-scale*m
__global__ void gin_ss(const float* __restrict__ stats, const float* __restrict__ gamma,
                       const float* __restrict__ beta, float* __restrict__ ss, float invN) {
    int d = threadIdx.x;
    if (d < DIM) {
        float m = stats[d] * invN;
        float var = stats[DIM + d] * invN - m * m;
        float sc = gamma[d] * rsqrtf(var + BN_EPS);
        ss[d] = sc;
        ss[DIM + d] = beta[d] - sc * m;
    }
}

__global__ void gin_ss_init(float* __restrict__ ss) {
    int t = threadIdx.x;  // 128 threads
    ss[t] = (t < DIM) ? 1.f : 0.f;
}

// pool with folded BN3: one wave per graph (batch sorted -> binary search range),
// direct write to d_out with dtype cast. No atomics.
__global__ void gin_pool(const float* __restrict__ h, const int* __restrict__ batch,
                         const float* __restrict__ ss, void* __restrict__ out,
                         int N, int G, const int* __restrict__ flag) {
    int gw = (blockIdx.x * blockDim.x + threadIdx.x) >> 6;
    int lane = threadIdx.x & 63;
    if (gw >= G) return;
    int lo = 0, hi = N;
    while (lo < hi) { int mid = (lo + hi) >> 1; if (batch[mid] < gw) lo = mid + 1; else hi = mid; }
    int s0 = lo;
    hi = N;
    while (lo < hi) { int mid = (lo + hi) >> 1; if (batch[mid] < gw + 1) lo = mid + 1; else hi = mid; }
    int s1 = lo;
    float a0 = 0.f, a1 = 0.f, a2 = 0.f, a3 = 0.f;
    int n = s0;
    for (; n + 3 < s1; n += 4) {
        a0 += h[n * DIM + lane];
        a1 += h[(n + 1) * DIM + lane];
        a2 += h[(n + 2) * DIM + lane];
        a3 += h[(n + 3) * DIM + lane];
    }
    for (; n < s1; n++) a0 += h[n * DIM + lane];
    float acc = (a0 + a1) + (a2 + a3);
    float v = ss[lane] * acc + (float)(s1 - s0) * ss[DIM + lane];
    int f = flag[0];
    if (f) ((bf16*)out)[gw * DIM + lane] = __float2bfloat16(v);
    else   ((float*)out)[gw * DIM + lane] = v;
}

extern "C" void kernel_launch(void* const* d_in, const int* in_sizes, int n_in,
                              void* d_out, int out_size, void* d_ws, size_t ws_size,
                              hipStream_t stream) {
    (void)hipGetLastError();  // clear any stale error

    const int N = in_sizes[0] / DIM;   // F_IN == DIM == 64
    const int E = in_sizes[1] / 2;
    const int G = out_size / DIM;
    const size_t ND = (size_t)N * DIM;

    const void* x     = d_in[0];
    const int*  ei    = (const int*)d_in[1];
    const int*  srcp  = ei;
    const int*  dstp  = ei + E;
    const int*  batch = (const int*)d_in[2];

    // workspace layout
    int*   flag   = (int*)d_ws;
    float* P      = (float*)d_ws + 64;         // staged f32 params (25344 used)
    float* bufA   = P + 25600;                 // h
    float* bufB   = bufA + ND;                 // gathered / mid
    float* stats  = bufB + ND;                 // [128]
    float* ss     = stats + 128;               // [128] scale|shift
    int*   rowptr = (int*)(ss + 128);          // [N+1]
    int*   deg    = rowptr + (N + 1);          // [N] (reused as fill cursor)
    int*   part   = deg + N;                   // [1024]
    int*   adj    = part + 1024;               // [E]
    size_t need = ((size_t)64 + 25600 + 2 * ND + 256) * sizeof(float)
                + ((size_t)(N + 1) + N + 1024 + E) * sizeof(int);
    if (ws_size < need) {  // "workspace too small" marker: err prints ~5e33
        hipMemsetAsync(d_out, 0x77, (size_t)out_size * 2, stream);
        return;
    }

    // param staging pack: per layer {wa, ba, wb, bb, gamma, beta}
    ParamPack pk;
    int off = 0;
    for (int l = 0; l < 3; l++) {
        for (int j = 0; j < 6; j++) {
            int idx = 3 + 6 * l + j;
            pk.p[6 * l + j]   = d_in[idx];
            pk.n[6 * l + j]   = in_sizes[idx];
            pk.off[6 * l + j] = off;
            off += in_sizes[idx];
        }
    }
    float* wa[3], *ba[3], *wb[3], *bb[3], *gm[3], *be[3];
    for (int l = 0; l < 3; l++) {
        float* base = P + l * 8448;
        wa[l] = base;        ba[l] = base + 4096;
        wb[l] = base + 4160; bb[l] = base + 8256;
        gm[l] = base + 8320; be[l] = base + 8384;
    }

    const int TB = 256;
    const int grid_nd = (int)((ND + TB - 1) / TB);
    const int grid_n  = (N + TB - 1) / TB;
    const int grid_e  = (E + TB - 1) / TB;
    const int grid_g  = (G * DIM + TB - 1) / TB;
    const int NB      = (N + 1023) / 1024;
    const int grid_mlp = (N + 63) / 64;

    gin_detect<<<1, 256, 0, stream>>>(d_in[3], in_sizes[3], flag);
    gin_cvt_params<<<18, 256, 0, stream>>>(pk, P, flag);
    GINEncoder_16114717295311_kernel<<<grid_nd, TB, 0, stream>>>(x, bufA, (int)ND, flag);

    // CSR build (once; reused by all 3 layers)
    gin_zero<<<grid_n, TB, 0, stream>>>((float*)deg, N);
    gin_hist<<<grid_e, TB, 0, stream>>>(dstp, deg, E);
    gin_scan1<<<NB, 256, 0, stream>>>(deg, rowptr, part, N);
    gin_scan2<<<1, 256, 0, stream>>>(part, NB);
    gin_scan3<<<grid_n, TB, 0, stream>>>(rowptr, part, N);
    gin_zero<<<grid_n, TB, 0, stream>>>((float*)deg, N);  // deg -> cursor
    gin_fill<<<grid_e, TB, 0, stream>>>(srcp, dstp, rowptr, deg, adj, E);

    gin_ss_init<<<1, 128, 0, stream>>>(ss);
    for (int l = 0; l < 3; l++) {
        gin_gather<<<2048, TB, 0, stream>>>(bufA, bufB, rowptr, adj, ss, N);
        gin_zero<<<1, 128, 0, stream>>>(stats, 128);
        gin_mlp<<<grid_mlp, TB, 0, stream>>>(bufB, bufA, wa[l], ba[l], wb[l], bb[l], stats, N);
        gin_ss<<<1, 64, 0, stream>>>(stats, gm[l], be[l], ss, 1.0f / (float)N);
    }

    gin_pool<<<grid_g, TB, 0, stream>>>(bufA, batch, ss, d_out, N, G, flag);

    // "some launch failed" marker: err prints ~1.7e38 (bf16) / 3.4e38 (f32)
    hipError_t e = hipGetLastError();
    if (e != hipSuccess) {
        hipMemsetAsync(d_out, 0x7F, (size_t)out_size * 2, stream);
    }
}